// Round 13
// baseline (687.802 us; speedup 1.0000x reference)
//
#include <hip/hip_runtime.h>
#include <stdint.h>

typedef unsigned short u16;
typedef unsigned int u32;
typedef unsigned long long u64;
typedef __attribute__((ext_vector_type(4))) u16 u16x4;
typedef __attribute__((ext_vector_type(8))) u16 u16x8;
typedef __attribute__((ext_vector_type(2))) u32 u32x2;
typedef __attribute__((ext_vector_type(8))) short bf16x8;
typedef __attribute__((ext_vector_type(4))) float f32x4;

#define DEVFN __device__ __forceinline__

DEVFN u16 f2bf(float f) {
  union { float f; u32 u; } x; x.f = f;
  u32 u = x.u;
  return (u16)((u + 0x7fffu + ((u >> 16) & 1u)) >> 16);
}
DEVFN float bf2f(u16 v) {
  union { u32 u; float f; } x; x.u = ((u32)v) << 16;
  return x.f;
}
// packed f32->bf16 RNE (same rounding as f2bf); lo -> low word
DEVFN u32 cvtpk(float lo, float hi) {
  u32 r;
  asm("v_cvt_pk_bf16_f32 %0, %1, %2" : "=v"(r) : "v"(lo), "v"(hi));
  return r;
}

// ---------------- fp32 -> bf16 convert ----------------
__global__ void cvt_kernel(const float* __restrict__ in, u16* __restrict__ out, int n4) {
  const int stride = gridDim.x * blockDim.x;
  for (int i = blockIdx.x * blockDim.x + threadIdx.x; i < n4; i += stride) {
    float4 v = reinterpret_cast<const float4*>(in)[i];
    u16x4 o;
    o.x = f2bf(v.x); o.y = f2bf(v.y); o.z = f2bf(v.z); o.w = f2bf(v.w);
    reinterpret_cast<u16x4*>(out)[i] = o;
  }
}

// ---------------- padded bias table, bf16: pbb[h][i][j64] (pad = 0) ----------------
__global__ void pbb_kernel(const float* __restrict__ bt, const int* __restrict__ ri,
                           u16* __restrict__ pbb) {
  const int h = blockIdx.x;
  for (int t = threadIdx.x; t < 4096; t += 256) {
    const int i = t >> 6, j = t & 63;
    float v = 0.f;
    if (i < 49 && j < 49) v = bt[ri[i * 49 + j] * 16 + h];
    pbb[h * 4096 + t] = f2bf(v);
  }
}

// ---------------- bit-packed mask: mbits[w][i] bit j set == masked (-100) ----------------
__global__ void mbits_kernel(const float* __restrict__ mask, u64* __restrict__ mb) {
  const int w = blockIdx.x;
  const int i = threadIdx.x;  // 0..63
  u64 m = ~0ull << 49;
  if (i < 49) {
    for (int j = 0; j < 49; ++j)
      if (mask[w * 2401 + i * 49 + j] < -1.0f) m |= 1ull << j;
  } else {
    m = ~0ull;
  }
  mb[w * 64 + i] = m;
}

// ---------------- bf16 GEMM: C = A @ Bt^T + bias, K=512 fixed ----------------
// r8 structure (proven 199-201 us, 0 bank conflicts): 256x256 tile, 8 waves,
// BK=64, dbuf 128 KB LDS, 4 phases/K-tile, stage stream s=g-3, VM2 tail.
// Prologue: vmcnt(8) (tile 0 = oldest 8 of 16 forced down; tile 1 stays in
// flight -- kt0 P4's VM2 forces tile 1 fully before kt1 P1: all-parts rule OK).
#define WAIT_LGKM0 asm volatile("s_waitcnt lgkmcnt(0)" ::: "memory")
#define WAIT_LGKM8 asm volatile("s_waitcnt lgkmcnt(8)" ::: "memory")
#define WAIT_VM8   asm volatile("s_waitcnt vmcnt(8)" ::: "memory")
#define WAIT_VM2   asm volatile("s_waitcnt vmcnt(2)" ::: "memory")
#define WAIT_VM0   asm volatile("s_waitcnt vmcnt(0)" ::: "memory")
#define SCHEDB     __builtin_amdgcn_sched_barrier(0)
#define BARRIER    __builtin_amdgcn_s_barrier()
#define MFMA(a, b, c) __builtin_amdgcn_mfma_f32_16x16x32_bf16(a, b, c, 0, 0, 0)

template <int MODE, int NTILES, int MCHUNK>
__global__ __launch_bounds__(512) void gemm_kernel(
    const u16* __restrict__ A, const u16* __restrict__ Bt,
    const float* __restrict__ bias, void* __restrict__ Out, int ldo) {
  extern __shared__ u16 smem[];  // per buffer: A 256x64 | B 256x64 (32768 u16); 2 buffers
  const int tid = threadIdx.x;
  const int lane = tid & 63;
  const int wid = tid >> 6;
  const int bid = blockIdx.x;
  const int xcd = bid & 7;
  const int slot = bid >> 3;
  const int m0 = (xcd * MCHUNK + slot / NTILES) * 256;
  const int n0 = (slot % NTILES) * 256;
  const int wr = wid >> 2, wc = wid & 3;  // wave -> (2M x 4N)
  const int l15 = lane & 15, lg = lane >> 4;
  const int rg0 = tid >> 3;  // staging row within 64-row round
  const int sl0 = tid & 7;   // staging 16B slot within 128B row

  f32x4 acc[8][4] = {};

  // half parts: 0=A rows 0-127, 1=A rows 128-255, 2=B rows 0-127, 3=B rows 128-255
#define STAGE_RAW(kt_, hp_)                                                    \
  {                                                                            \
    const u16* srcp_ = ((hp_) < 2)                                             \
        ? (A + (size_t)(m0 + ((hp_) & 1) * 128) * 512)                         \
        : (Bt + (size_t)(n0 + ((hp_) & 1) * 128) * 512);                       \
    u16* dst_ = smem + ((kt_) & 1) * 32768 + (hp_) * 8192;                     \
    _Pragma("unroll") for (int i_ = 0; i_ < 2; ++i_) {                         \
      const int rg_ = i_ * 64 + rg0;                                           \
      const int kc_ = sl0 ^ (rg_ & 7);                                         \
      const u16* g_ = srcp_ + (size_t)rg_ * 512 + (kt_) * 64 + kc_ * 8;        \
      __builtin_amdgcn_global_load_lds(                                        \
          (const __attribute__((address_space(1))) void*)g_,                   \
          (__attribute__((address_space(3))) void*)(dst_ + i_ * 4096 + wid * 512), \
          16, 0, 0);                                                           \
    }                                                                          \
  }

  // stage stream: s-th half-tile (s = g-3, g = global phase) = K-tile 2+s/4, part s&3
#define STG(g_)                                                                \
  if ((g_) >= 3 && (g_) < 27) {                                                \
    const int s_ = (g_) - 3;                                                   \
    STAGE_RAW(2 + s_ / 4, s_ & 3);                                             \
  }

#define RDA(dst, mi_, ks_)                                                     \
  {                                                                            \
    const int row_ = wr * 128 + (mi_) * 16 + l15;                              \
    dst = *reinterpret_cast<const bf16x8*>(                                    \
        smem + cb + row_ * 64 + ((((ks_) * 4 + lg) ^ (row_ & 7)) << 3));       \
  }
#define RDB(dst, ni_, ks_)                                                     \
  {                                                                            \
    const int row_ = wc * 64 + (ni_) * 16 + l15;                               \
    dst = *reinterpret_cast<const bf16x8*>(                                    \
        smem + cb + 16384 + row_ * 64 + ((((ks_) * 4 + lg) ^ (row_ & 7)) << 3)); \
  }

  // prologue: K-tiles 0,1 staged; only tile 0 forced down (tile 1 in flight)
#pragma unroll
  for (int hp = 0; hp < 4; ++hp) STAGE_RAW(0, hp);
#pragma unroll
  for (int hp = 0; hp < 4; ++hp) STAGE_RAW(1, hp);
  WAIT_VM8; SCHEDB;
  BARRIER; SCHEDB;

#pragma unroll
  for (int kt = 0; kt < 8; ++kt) {
    const int cb = (kt & 1) * 32768;
    const int g0 = kt * 4;
    bf16x8 a0[4][2], a1[4][2], b0[2][2], b1[2][2];

    // ---- P1: reads A-low(8) + B-low(4); quad (M0,N0) ----
#pragma unroll
    for (int mi = 0; mi < 4; ++mi) { RDA(a0[mi][0], mi, 0); RDA(a0[mi][1], mi, 1); }
#pragma unroll
    for (int ni = 0; ni < 2; ++ni) { RDB(b0[ni][0], ni, 0); RDB(b0[ni][1], ni, 1); }
    STG(g0 + 0);
    WAIT_LGKM8; SCHEDB;
    BARRIER;
    WAIT_LGKM0; SCHEDB;
    __builtin_amdgcn_s_setprio(1);
#pragma unroll
    for (int mi = 0; mi < 4; ++mi)
#pragma unroll
      for (int ni = 0; ni < 2; ++ni)
#pragma unroll
        for (int ks = 0; ks < 2; ++ks)
          acc[mi][ni] = MFMA(a0[mi][ks], b0[ni][ks], acc[mi][ni]);
    __builtin_amdgcn_s_setprio(0); SCHEDB;
    BARRIER; SCHEDB;

    // ---- P2: reads B-high(4); quad (M0,N1) ----
#pragma unroll
    for (int ni = 0; ni < 2; ++ni) { RDB(b1[ni][0], ni + 2, 0); RDB(b1[ni][1], ni + 2, 1); }
    STG(g0 + 1);
    BARRIER;
    WAIT_LGKM0; SCHEDB;
    __builtin_amdgcn_s_setprio(1);
#pragma unroll
    for (int mi = 0; mi < 4; ++mi)
#pragma unroll
      for (int ni = 0; ni < 2; ++ni)
#pragma unroll
        for (int ks = 0; ks < 2; ++ks)
          acc[mi][ni + 2] = MFMA(a0[mi][ks], b1[ni][ks], acc[mi][ni + 2]);
    __builtin_amdgcn_s_setprio(0); SCHEDB;
    BARRIER; SCHEDB;

    // ---- P3: reads A-high(8); quad (M1,N1) ----
#pragma unroll
    for (int mi = 0; mi < 4; ++mi) { RDA(a1[mi][0], mi + 4, 0); RDA(a1[mi][1], mi + 4, 1); }
    STG(g0 + 2);
    BARRIER;
    WAIT_LGKM0; SCHEDB;
    __builtin_amdgcn_s_setprio(1);
#pragma unroll
    for (int mi = 0; mi < 4; ++mi)
#pragma unroll
      for (int ni = 0; ni < 2; ++ni)
#pragma unroll
        for (int ks = 0; ks < 2; ++ks)
          acc[mi + 4][ni + 2] = MFMA(a1[mi][ks], b1[ni][ks], acc[mi + 4][ni + 2]);
    __builtin_amdgcn_s_setprio(0); SCHEDB;
    BARRIER; SCHEDB;

    // ---- P4: no reads; quad (M1,N0) from live regs; vmcnt once per K-tile ----
    STG(g0 + 3);
    BARRIER; SCHEDB;
    __builtin_amdgcn_s_setprio(1);
#pragma unroll
    for (int mi = 0; mi < 4; ++mi)
#pragma unroll
      for (int ni = 0; ni < 2; ++ni)
#pragma unroll
        for (int ks = 0; ks < 2; ++ks)
          acc[mi + 4][ni] = MFMA(a1[mi][ks], b0[ni][ks], acc[mi + 4][ni]);
    __builtin_amdgcn_s_setprio(0); SCHEDB;
    if (g0 + 3 == 27) { WAIT_VM0; }            // drain last prefetch (K7)
    else if (g0 + 3 < 27) { WAIT_VM2; }        // confirm next K-tile's 4 halves
    SCHEDB;
    BARRIER; SCHEDB;
  }
#undef STAGE_RAW
#undef STG
#undef RDA
#undef RDB

#pragma unroll
  for (int mi = 0; mi < 8; ++mi) {
#pragma unroll
    for (int ni = 0; ni < 4; ++ni) {
      const int col = n0 + wc * 64 + ni * 16 + l15;
      const float bv = bias[col];
      const int rbase = m0 + wr * 128 + mi * 16 + lg * 4;
#pragma unroll
      for (int r = 0; r < 4; ++r) {
        const float v = acc[mi][ni][r] + bv;
        if (MODE == 0) {
          ((u16*)Out)[(size_t)(rbase + r) * ldo + col] = f2bf(v);  // plain: bf16 NT amplifies (r11)
        } else {
          __builtin_nontemporal_store(v, &((float*)Out)[(size_t)(rbase + r) * ldo + col]);
        }
      }
    }
  }
}

// ---------------- attention: one wave per (window, head), 4 heads/block ----------------
// Swapped QK^T (S^T = K@Q^T) makes softmax j-axis lane-local; V stored pi-permuted in
// LDS so the PV A-fragment is the lane's own packed P values: no barriers, no sP.
// launch_bounds(256,8): VGPR<=64 -> 8 waves/SIMD (was 6 @80 VGPR) -- latency-bound
// kernel, concurrency is the multiplier. P-packing via v_cvt_pk_bf16_f32 (T12).
__global__ __launch_bounds__(256, 8) void attn_kernel(
    const u16* __restrict__ qkv, const u16* __restrict__ pbb,
    const u64* __restrict__ mbits, u16* __restrict__ attn_out) {
  const int w = threadIdx.x >> 6;
  const int lane = threadIdx.x & 63;
  const int xcd = blockIdx.x & 7;
  const int rest = blockIdx.x >> 3;       // 0..1023
  const int b = xcd * 256 + (rest >> 2);  // window
  const int h = ((rest & 3) << 2) | w;
  const int l15 = lane & 15, lg = lane >> 4;
  const int lg4 = lg * 4;

  __shared__ u16 sVT[4][32][72];
  u16 (*vt)[72] = sVT[w];

  for (int i = lane; i < 1152; i += 64) ((u32*)vt)[i] = 0;

  const size_t rowbase = (size_t)b * (49 * 1536) + h * 32;

  for (int c = lane; c < 196; c += 64) {
    const int n = c >> 2, dg = c & 3;
    u16x8 vv = *reinterpret_cast<const u16x8*>(qkv + rowbase + (size_t)n * 1536 + 1024 + dg * 8);
    const int pin = ((n >> 5) << 5) | ((((n >> 2) & 3)) << 3) | (((n >> 4) & 1) << 2) | (n & 3);
#pragma unroll
    for (int j = 0; j < 8; ++j) vt[dg * 8 + j][pin] = vv[j];
  }

  bf16x8 aq[4], bk[4];
#pragma unroll
  for (int t = 0; t < 4; ++t) {
    const int i = t * 16 + l15;
    const int r = i < 49 ? i : 48;
    const size_t ro = rowbase + (size_t)r * 1536 + lg * 8;
    aq[t] = *reinterpret_cast<const bf16x8*>(qkv + ro);
    bk[t] = *reinterpret_cast<const bf16x8*>(qkv + ro + 512);
  }

  const u64* mwb = mbits + ((b & 63) << 6);
  u64 mb[4];
#pragma unroll
  for (int qt = 0; qt < 4; ++qt) mb[qt] = mwb[qt * 16 + l15];

  bf16x8 bv[2][2];
#pragma unroll
  for (int ni = 0; ni < 2; ++ni)
#pragma unroll
    for (int ks = 0; ks < 2; ++ks)
      bv[ni][ks] = *reinterpret_cast<const bf16x8*>(&vt[ni * 16 + l15][ks * 32 + lg * 8]);

  const float scale = 0.17677669529663687f;
  const u16* pbh = pbb + (h << 12);
  const size_t obase = (size_t)b * 49 * 512 + h * 32;

#pragma unroll
  for (int qt = 0; qt < 4; ++qt) {
    f32x4 sT[4] = {};
#pragma unroll
    for (int kt = 0; kt < 4; ++kt)
      sT[kt] = __builtin_amdgcn_mfma_f32_16x16x32_bf16(bk[kt], aq[qt], sT[kt], 0, 0, 0);

    const int i = qt * 16 + l15;
    const u16* pr = pbh + i * 64 + lg4;
    float v[4][4];
    float mx = -3e38f;
#pragma unroll
    for (int kt = 0; kt < 4; ++kt) {
      u16x4 pv = *reinterpret_cast<const u16x4*>(pr + kt * 16);
      const u32 nib = (u32)(mb[qt] >> (kt * 16 + lg4)) & 0xFu;
#pragma unroll
      for (int r = 0; r < 4; ++r) {
        float val = fmaf(sT[kt][r], scale, bf2f(pv[r]));
        if (nib & (1u << r)) val -= 100.f;
        if (kt == 3 && (lg4 + r) >= 1) val = -1e30f;
        v[kt][r] = val;
        mx = fmaxf(mx, val);
      }
    }
    mx = fmaxf(mx, __shfl_xor(mx, 16));
    mx = fmaxf(mx, __shfl_xor(mx, 32));
    float sum = 0.f;
#pragma unroll
    for (int kt = 0; kt < 4; ++kt)
#pragma unroll
      for (int r = 0; r < 4; ++r) {
        const float e = __expf(v[kt][r] - mx);
        v[kt][r] = e;
        sum += e;
      }
    sum += __shfl_xor(sum, 16);
    sum += __shfl_xor(sum, 32);
    const float rinv = 1.0f / sum;

    bf16x8 ap[2];
#pragma unroll
    for (int ks = 0; ks < 2; ++ks) {
      union { u32 u[4]; bf16x8 b; } pk;
      pk.u[0] = cvtpk(v[2 * ks][0] * rinv, v[2 * ks][1] * rinv);
      pk.u[1] = cvtpk(v[2 * ks][2] * rinv, v[2 * ks][3] * rinv);
      pk.u[2] = cvtpk(v[2 * ks + 1][0] * rinv, v[2 * ks + 1][1] * rinv);
      pk.u[3] = cvtpk(v[2 * ks + 1][2] * rinv, v[2 * ks + 1][3] * rinv);
      ap[ks] = pk.b;
    }

    f32x4 o[2] = {};
#pragma unroll
    for (int ks = 0; ks < 2; ++ks)
#pragma unroll
      for (int ni = 0; ni < 2; ++ni)
        o[ni] = __builtin_amdgcn_mfma_f32_16x16x32_bf16(ap[ks], bv[ni][ks], o[ni], 0, 0, 0);

#pragma unroll
    for (int r = 0; r < 4; ++r) {
      const int iq = qt * 16 + lg4 + r;
      if (iq < 49) {
#pragma unroll
        for (int ni = 0; ni < 2; ++ni)
          attn_out[obase + (size_t)iq * 512 + ni * 16 + l15] = f2bf(o[ni][r]);
      }
    }
  }
}

extern "C" void kernel_launch(void* const* d_in, const int* in_sizes, int n_in,
                              void* d_out, int out_size, void* d_ws, size_t ws_size,
                              hipStream_t stream) {
  (void)in_sizes; (void)n_in; (void)out_size; (void)ws_size;
  const float* x          = (const float*)d_in[0];
  const float* w_qkv      = (const float*)d_in[1];
  const float* b_qkv      = (const float*)d_in[2];
  const float* w_proj     = (const float*)d_in[3];
  const float* b_proj     = (const float*)d_in[4];
  const float* bias_table = (const float*)d_in[5];
  const int*   rel_index  = (const int*)d_in[6];
  const float* mask       = (const float*)d_in[7];

  u16* ws     = (u16*)d_ws;
  u16* xbf    = ws;                    // 51,380,224 elems (reused as attn_out)
  u16* qkv    = ws + 51380224;         // 154,140,672 elems
  u16* wqkvb  = qkv + 154140672;       // 786,432 elems
  u16* wprojb = wqkvb + 786432;        // 262,144 elems
  u16* pbb    = wprojb + 262144;       // 16*4096 bf16 (128 KB)
  u64* mbits  = (u64*)(pbb + 65536);   // 64*64 u64 (32 KB), 8B-aligned

  (void)hipFuncSetAttribute((const void*)gemm_kernel<0, 6, 49>,
                            hipFuncAttributeMaxDynamicSharedMemorySize, 131072);
  (void)hipFuncSetAttribute((const void*)gemm_kernel<1, 2, 49>,
                            hipFuncAttributeMaxDynamicSharedMemorySize, 131072);

  cvt_kernel<<<2048, 256, 0, stream>>>(x, xbf, 51380224 / 4);
  cvt_kernel<<<192, 256, 0, stream>>>(w_qkv, wqkvb, 786432 / 4);
  cvt_kernel<<<64, 256, 0, stream>>>(w_proj, wprojb, 262144 / 4);
  pbb_kernel<<<16, 256, 0, stream>>>(bias_table, rel_index, pbb);
  mbits_kernel<<<64, 64, 0, stream>>>(mask, mbits);

  // 392 m-tiles = 8 XCDs * 49; GEMM1: 6 n-tiles of 256, GEMM2: 2 n-tiles
  gemm_kernel<0, 6, 49><<<2352, 512, 131072, stream>>>(xbf, wqkvb, b_qkv, qkv, 1536);
  attn_kernel<<<8192, 256, 0, stream>>>(qkv, pbb, mbits, xbf);
  gemm_kernel<1, 2, 49><<<784, 512, 131072, stream>>>(xbf, wprojb, b_proj, d_out, 512);
}

// Round 14
// 506.585 us; speedup vs baseline: 1.3577x; 1.3577x over previous
//
#include <hip/hip_runtime.h>
#include <stdint.h>

typedef unsigned short u16;
typedef unsigned int u32;
typedef unsigned long long u64;
typedef __attribute__((ext_vector_type(4))) u16 u16x4;
typedef __attribute__((ext_vector_type(8))) u16 u16x8;
typedef __attribute__((ext_vector_type(2))) u32 u32x2;
typedef __attribute__((ext_vector_type(8))) short bf16x8;
typedef __attribute__((ext_vector_type(4))) float f32x4;

#define DEVFN __device__ __forceinline__

DEVFN u16 f2bf(float f) {
  union { float f; u32 u; } x; x.f = f;
  u32 u = x.u;
  return (u16)((u + 0x7fffu + ((u >> 16) & 1u)) >> 16);
}
DEVFN float bf2f(u16 v) {
  union { u32 u; float f; } x; x.u = ((u32)v) << 16;
  return x.f;
}
// packed f32->bf16 RNE (same rounding as f2bf); lo -> low word
DEVFN u32 cvtpk(float lo, float hi) {
  u32 r;
  asm("v_cvt_pk_bf16_f32 %0, %1, %2" : "=v"(r) : "v"(lo), "v"(hi));
  return r;
}

// ---------------- fp32 -> bf16 convert ----------------
__global__ void cvt_kernel(const float* __restrict__ in, u16* __restrict__ out, int n4) {
  const int stride = gridDim.x * blockDim.x;
  for (int i = blockIdx.x * blockDim.x + threadIdx.x; i < n4; i += stride) {
    float4 v = reinterpret_cast<const float4*>(in)[i];
    u16x4 o;
    o.x = f2bf(v.x); o.y = f2bf(v.y); o.z = f2bf(v.z); o.w = f2bf(v.w);
    reinterpret_cast<u16x4*>(out)[i] = o;
  }
}

// ---------------- padded bias table, bf16: pbb[h][i][j64] (pad = 0) ----------------
__global__ void pbb_kernel(const float* __restrict__ bt, const int* __restrict__ ri,
                           u16* __restrict__ pbb) {
  const int h = blockIdx.x;
  for (int t = threadIdx.x; t < 4096; t += 256) {
    const int i = t >> 6, j = t & 63;
    float v = 0.f;
    if (i < 49 && j < 49) v = bt[ri[i * 49 + j] * 16 + h];
    pbb[h * 4096 + t] = f2bf(v);
  }
}

// ---------------- bit-packed mask: mbits[w][i] bit j set == masked (-100) ----------------
__global__ void mbits_kernel(const float* __restrict__ mask, u64* __restrict__ mb) {
  const int w = blockIdx.x;
  const int i = threadIdx.x;  // 0..63
  u64 m = ~0ull << 49;
  if (i < 49) {
    for (int j = 0; j < 49; ++j)
      if (mask[w * 2401 + i * 49 + j] < -1.0f) m |= 1ull << j;
  } else {
    m = ~0ull;
  }
  mb[w * 64 + i] = m;
}

// ---------------- bf16 GEMM: C = A @ Bt^T + bias, K=512 fixed ----------------
// r8 structure (proven 199-201 us, 0 bank conflicts): 256x256 tile, 8 waves,
// BK=64, dbuf 128 KB LDS, 4 phases/K-tile, stage stream s=g-3, VM2 tail.
// Prologue: vmcnt(8) (tile 0 = oldest 8 of 16 forced down; tile 1 stays in
// flight -- kt0 P4's VM2 forces tile 1 fully before kt1 P1: all-parts rule OK).
#define WAIT_LGKM0 asm volatile("s_waitcnt lgkmcnt(0)" ::: "memory")
#define WAIT_LGKM8 asm volatile("s_waitcnt lgkmcnt(8)" ::: "memory")
#define WAIT_VM8   asm volatile("s_waitcnt vmcnt(8)" ::: "memory")
#define WAIT_VM2   asm volatile("s_waitcnt vmcnt(2)" ::: "memory")
#define WAIT_VM0   asm volatile("s_waitcnt vmcnt(0)" ::: "memory")
#define SCHEDB     __builtin_amdgcn_sched_barrier(0)
#define BARRIER    __builtin_amdgcn_s_barrier()
#define MFMA(a, b, c) __builtin_amdgcn_mfma_f32_16x16x32_bf16(a, b, c, 0, 0, 0)

template <int MODE, int NTILES, int MCHUNK>
__global__ __launch_bounds__(512) void gemm_kernel(
    const u16* __restrict__ A, const u16* __restrict__ Bt,
    const float* __restrict__ bias, void* __restrict__ Out, int ldo) {
  extern __shared__ u16 smem[];  // per buffer: A 256x64 | B 256x64 (32768 u16); 2 buffers
  const int tid = threadIdx.x;
  const int lane = tid & 63;
  const int wid = tid >> 6;
  const int bid = blockIdx.x;
  const int xcd = bid & 7;
  const int slot = bid >> 3;
  const int m0 = (xcd * MCHUNK + slot / NTILES) * 256;
  const int n0 = (slot % NTILES) * 256;
  const int wr = wid >> 2, wc = wid & 3;  // wave -> (2M x 4N)
  const int l15 = lane & 15, lg = lane >> 4;
  const int rg0 = tid >> 3;  // staging row within 64-row round
  const int sl0 = tid & 7;   // staging 16B slot within 128B row

  f32x4 acc[8][4] = {};

  // half parts: 0=A rows 0-127, 1=A rows 128-255, 2=B rows 0-127, 3=B rows 128-255
#define STAGE_RAW(kt_, hp_)                                                    \
  {                                                                            \
    const u16* srcp_ = ((hp_) < 2)                                             \
        ? (A + (size_t)(m0 + ((hp_) & 1) * 128) * 512)                         \
        : (Bt + (size_t)(n0 + ((hp_) & 1) * 128) * 512);                       \
    u16* dst_ = smem + ((kt_) & 1) * 32768 + (hp_) * 8192;                     \
    _Pragma("unroll") for (int i_ = 0; i_ < 2; ++i_) {                         \
      const int rg_ = i_ * 64 + rg0;                                           \
      const int kc_ = sl0 ^ (rg_ & 7);                                         \
      const u16* g_ = srcp_ + (size_t)rg_ * 512 + (kt_) * 64 + kc_ * 8;        \
      __builtin_amdgcn_global_load_lds(                                        \
          (const __attribute__((address_space(1))) void*)g_,                   \
          (__attribute__((address_space(3))) void*)(dst_ + i_ * 4096 + wid * 512), \
          16, 0, 0);                                                           \
    }                                                                          \
  }

  // stage stream: s-th half-tile (s = g-3, g = global phase) = K-tile 2+s/4, part s&3
#define STG(g_)                                                                \
  if ((g_) >= 3 && (g_) < 27) {                                                \
    const int s_ = (g_) - 3;                                                   \
    STAGE_RAW(2 + s_ / 4, s_ & 3);                                             \
  }

#define RDA(dst, mi_, ks_)                                                     \
  {                                                                            \
    const int row_ = wr * 128 + (mi_) * 16 + l15;                              \
    dst = *reinterpret_cast<const bf16x8*>(                                    \
        smem + cb + row_ * 64 + ((((ks_) * 4 + lg) ^ (row_ & 7)) << 3));       \
  }
#define RDB(dst, ni_, ks_)                                                     \
  {                                                                            \
    const int row_ = wc * 64 + (ni_) * 16 + l15;                               \
    dst = *reinterpret_cast<const bf16x8*>(                                    \
        smem + cb + 16384 + row_ * 64 + ((((ks_) * 4 + lg) ^ (row_ & 7)) << 3)); \
  }

  // prologue: K-tiles 0,1 staged; only tile 0 forced down (tile 1 in flight)
#pragma unroll
  for (int hp = 0; hp < 4; ++hp) STAGE_RAW(0, hp);
#pragma unroll
  for (int hp = 0; hp < 4; ++hp) STAGE_RAW(1, hp);
  WAIT_VM8; SCHEDB;
  BARRIER; SCHEDB;

#pragma unroll
  for (int kt = 0; kt < 8; ++kt) {
    const int cb = (kt & 1) * 32768;
    const int g0 = kt * 4;
    bf16x8 a0[4][2], a1[4][2], b0[2][2], b1[2][2];

    // ---- P1: reads A-low(8) + B-low(4); quad (M0,N0) ----
#pragma unroll
    for (int mi = 0; mi < 4; ++mi) { RDA(a0[mi][0], mi, 0); RDA(a0[mi][1], mi, 1); }
#pragma unroll
    for (int ni = 0; ni < 2; ++ni) { RDB(b0[ni][0], ni, 0); RDB(b0[ni][1], ni, 1); }
    STG(g0 + 0);
    WAIT_LGKM8; SCHEDB;
    BARRIER;
    WAIT_LGKM0; SCHEDB;
    __builtin_amdgcn_s_setprio(1);
#pragma unroll
    for (int mi = 0; mi < 4; ++mi)
#pragma unroll
      for (int ni = 0; ni < 2; ++ni)
#pragma unroll
        for (int ks = 0; ks < 2; ++ks)
          acc[mi][ni] = MFMA(a0[mi][ks], b0[ni][ks], acc[mi][ni]);
    __builtin_amdgcn_s_setprio(0); SCHEDB;
    BARRIER; SCHEDB;

    // ---- P2: reads B-high(4); quad (M0,N1) ----
#pragma unroll
    for (int ni = 0; ni < 2; ++ni) { RDB(b1[ni][0], ni + 2, 0); RDB(b1[ni][1], ni + 2, 1); }
    STG(g0 + 1);
    BARRIER;
    WAIT_LGKM0; SCHEDB;
    __builtin_amdgcn_s_setprio(1);
#pragma unroll
    for (int mi = 0; mi < 4; ++mi)
#pragma unroll
      for (int ni = 0; ni < 2; ++ni)
#pragma unroll
        for (int ks = 0; ks < 2; ++ks)
          acc[mi][ni + 2] = MFMA(a0[mi][ks], b1[ni][ks], acc[mi][ni + 2]);
    __builtin_amdgcn_s_setprio(0); SCHEDB;
    BARRIER; SCHEDB;

    // ---- P3: reads A-high(8); quad (M1,N1) ----
#pragma unroll
    for (int mi = 0; mi < 4; ++mi) { RDA(a1[mi][0], mi + 4, 0); RDA(a1[mi][1], mi + 4, 1); }
    STG(g0 + 2);
    BARRIER;
    WAIT_LGKM0; SCHEDB;
    __builtin_amdgcn_s_setprio(1);
#pragma unroll
    for (int mi = 0; mi < 4; ++mi)
#pragma unroll
      for (int ni = 0; ni < 2; ++ni)
#pragma unroll
        for (int ks = 0; ks < 2; ++ks)
          acc[mi + 4][ni + 2] = MFMA(a1[mi][ks], b1[ni][ks], acc[mi + 4][ni + 2]);
    __builtin_amdgcn_s_setprio(0); SCHEDB;
    BARRIER; SCHEDB;

    // ---- P4: no reads; quad (M1,N0) from live regs; vmcnt once per K-tile ----
    STG(g0 + 3);
    BARRIER; SCHEDB;
    __builtin_amdgcn_s_setprio(1);
#pragma unroll
    for (int mi = 0; mi < 4; ++mi)
#pragma unroll
      for (int ni = 0; ni < 2; ++ni)
#pragma unroll
        for (int ks = 0; ks < 2; ++ks)
          acc[mi + 4][ni] = MFMA(a1[mi][ks], b0[ni][ks], acc[mi + 4][ni]);
    __builtin_amdgcn_s_setprio(0); SCHEDB;
    if (g0 + 3 == 27) { WAIT_VM0; }            // drain last prefetch (K7)
    else if (g0 + 3 < 27) { WAIT_VM2; }        // confirm next K-tile's 4 halves
    SCHEDB;
    BARRIER; SCHEDB;
  }
#undef STAGE_RAW
#undef STG
#undef RDA
#undef RDB

#pragma unroll
  for (int mi = 0; mi < 8; ++mi) {
#pragma unroll
    for (int ni = 0; ni < 4; ++ni) {
      const int col = n0 + wc * 64 + ni * 16 + l15;
      const float bv = bias[col];
      const int rbase = m0 + wr * 128 + mi * 16 + lg * 4;
#pragma unroll
      for (int r = 0; r < 4; ++r) {
        const float v = acc[mi][ni][r] + bv;
        if (MODE == 0) {
          ((u16*)Out)[(size_t)(rbase + r) * ldo + col] = f2bf(v);  // plain: bf16 NT amplifies (r11)
        } else {
          __builtin_nontemporal_store(v, &((float*)Out)[(size_t)(rbase + r) * ldo + col]);
        }
      }
    }
  }
}

// ---------------- attention: one wave per (window, head), 4 heads/block ----------------
// Swapped QK^T (S^T = K@Q^T) makes softmax j-axis lane-local; V stored pi-permuted in
// LDS so the PV A-fragment is the lane's own packed P values: no barriers, no sP.
// NATURAL register allocation (~80 VGPR): r13's forced (256,8) bound spilled to
// scratch (VGPR 32, +900 MB HBM traffic, 150->333 us). Do NOT re-add min-waves.
__global__ __launch_bounds__(256) void attn_kernel(
    const u16* __restrict__ qkv, const u16* __restrict__ pbb,
    const u64* __restrict__ mbits, u16* __restrict__ attn_out) {
  const int w = threadIdx.x >> 6;
  const int lane = threadIdx.x & 63;
  const int xcd = blockIdx.x & 7;
  const int rest = blockIdx.x >> 3;       // 0..1023
  const int b = xcd * 256 + (rest >> 2);  // window
  const int h = ((rest & 3) << 2) | w;
  const int l15 = lane & 15, lg = lane >> 4;
  const int lg4 = lg * 4;

  __shared__ u16 sVT[4][32][72];
  u16 (*vt)[72] = sVT[w];

  for (int i = lane; i < 1152; i += 64) ((u32*)vt)[i] = 0;

  const size_t rowbase = (size_t)b * (49 * 1536) + h * 32;

  for (int c = lane; c < 196; c += 64) {
    const int n = c >> 2, dg = c & 3;
    u16x8 vv = *reinterpret_cast<const u16x8*>(qkv + rowbase + (size_t)n * 1536 + 1024 + dg * 8);
    const int pin = ((n >> 5) << 5) | ((((n >> 2) & 3)) << 3) | (((n >> 4) & 1) << 2) | (n & 3);
#pragma unroll
    for (int j = 0; j < 8; ++j) vt[dg * 8 + j][pin] = vv[j];
  }

  bf16x8 aq[4], bk[4];
#pragma unroll
  for (int t = 0; t < 4; ++t) {
    const int i = t * 16 + l15;
    const int r = i < 49 ? i : 48;
    const size_t ro = rowbase + (size_t)r * 1536 + lg * 8;
    aq[t] = *reinterpret_cast<const bf16x8*>(qkv + ro);
    bk[t] = *reinterpret_cast<const bf16x8*>(qkv + ro + 512);
  }

  const u64* mwb = mbits + ((b & 63) << 6);
  u64 mb[4];
#pragma unroll
  for (int qt = 0; qt < 4; ++qt) mb[qt] = mwb[qt * 16 + l15];

  bf16x8 bv[2][2];
#pragma unroll
  for (int ni = 0; ni < 2; ++ni)
#pragma unroll
    for (int ks = 0; ks < 2; ++ks)
      bv[ni][ks] = *reinterpret_cast<const bf16x8*>(&vt[ni * 16 + l15][ks * 32 + lg * 8]);

  const float scale = 0.17677669529663687f;
  const u16* pbh = pbb + (h << 12);
  const size_t obase = (size_t)b * 49 * 512 + h * 32;

#pragma unroll
  for (int qt = 0; qt < 4; ++qt) {
    f32x4 sT[4] = {};
#pragma unroll
    for (int kt = 0; kt < 4; ++kt)
      sT[kt] = __builtin_amdgcn_mfma_f32_16x16x32_bf16(bk[kt], aq[qt], sT[kt], 0, 0, 0);

    const int i = qt * 16 + l15;
    const u16* pr = pbh + i * 64 + lg4;
    float v[4][4];
    float mx = -3e38f;
#pragma unroll
    for (int kt = 0; kt < 4; ++kt) {
      u16x4 pv = *reinterpret_cast<const u16x4*>(pr + kt * 16);
      const u32 nib = (u32)(mb[qt] >> (kt * 16 + lg4)) & 0xFu;
#pragma unroll
      for (int r = 0; r < 4; ++r) {
        float val = fmaf(sT[kt][r], scale, bf2f(pv[r]));
        if (nib & (1u << r)) val -= 100.f;
        if (kt == 3 && (lg4 + r) >= 1) val = -1e30f;
        v[kt][r] = val;
        mx = fmaxf(mx, val);
      }
    }
    mx = fmaxf(mx, __shfl_xor(mx, 16));
    mx = fmaxf(mx, __shfl_xor(mx, 32));
    float sum = 0.f;
#pragma unroll
    for (int kt = 0; kt < 4; ++kt)
#pragma unroll
      for (int r = 0; r < 4; ++r) {
        const float e = __expf(v[kt][r] - mx);
        v[kt][r] = e;
        sum += e;
      }
    sum += __shfl_xor(sum, 16);
    sum += __shfl_xor(sum, 32);
    const float rinv = 1.0f / sum;

    bf16x8 ap[2];
#pragma unroll
    for (int ks = 0; ks < 2; ++ks) {
      union { u32 u[4]; bf16x8 b; } pk;
      pk.u[0] = cvtpk(v[2 * ks][0] * rinv, v[2 * ks][1] * rinv);
      pk.u[1] = cvtpk(v[2 * ks][2] * rinv, v[2 * ks][3] * rinv);
      pk.u[2] = cvtpk(v[2 * ks + 1][0] * rinv, v[2 * ks + 1][1] * rinv);
      pk.u[3] = cvtpk(v[2 * ks + 1][2] * rinv, v[2 * ks + 1][3] * rinv);
      ap[ks] = pk.b;
    }

    f32x4 o[2] = {};
#pragma unroll
    for (int ks = 0; ks < 2; ++ks)
#pragma unroll
      for (int ni = 0; ni < 2; ++ni)
        o[ni] = __builtin_amdgcn_mfma_f32_16x16x32_bf16(ap[ks], bv[ni][ks], o[ni], 0, 0, 0);

#pragma unroll
    for (int r = 0; r < 4; ++r) {
      const int iq = qt * 16 + lg4 + r;
      if (iq < 49) {
#pragma unroll
        for (int ni = 0; ni < 2; ++ni)
          attn_out[obase + (size_t)iq * 512 + ni * 16 + l15] = f2bf(o[ni][r]);
      }
    }
  }
}

extern "C" void kernel_launch(void* const* d_in, const int* in_sizes, int n_in,
                              void* d_out, int out_size, void* d_ws, size_t ws_size,
                              hipStream_t stream) {
  (void)in_sizes; (void)n_in; (void)out_size; (void)ws_size;
  const float* x          = (const float*)d_in[0];
  const float* w_qkv      = (const float*)d_in[1];
  const float* b_qkv      = (const float*)d_in[2];
  const float* w_proj     = (const float*)d_in[3];
  const float* b_proj     = (const float*)d_in[4];
  const float* bias_table = (const float*)d_in[5];
  const int*   rel_index  = (const int*)d_in[6];
  const float* mask       = (const float*)d_in[7];

  u16* ws     = (u16*)d_ws;
  u16* xbf    = ws;                    // 51,380,224 elems (reused as attn_out)
  u16* qkv    = ws + 51380224;         // 154,140,672 elems
  u16* wqkvb  = qkv + 154140672;       // 786,432 elems
  u16* wprojb = wqkvb + 786432;        // 262,144 elems
  u16* pbb    = wprojb + 262144;       // 16*4096 bf16 (128 KB)
  u64* mbits  = (u64*)(pbb + 65536);   // 64*64 u64 (32 KB), 8B-aligned

  (void)hipFuncSetAttribute((const void*)gemm_kernel<0, 6, 49>,
                            hipFuncAttributeMaxDynamicSharedMemorySize, 131072);
  (void)hipFuncSetAttribute((const void*)gemm_kernel<1, 2, 49>,
                            hipFuncAttributeMaxDynamicSharedMemorySize, 131072);

  cvt_kernel<<<2048, 256, 0, stream>>>(x, xbf, 51380224 / 4);
  cvt_kernel<<<192, 256, 0, stream>>>(w_qkv, wqkvb, 786432 / 4);
  cvt_kernel<<<64, 256, 0, stream>>>(w_proj, wprojb, 262144 / 4);
  pbb_kernel<<<16, 256, 0, stream>>>(bias_table, rel_index, pbb);
  mbits_kernel<<<64, 64, 0, stream>>>(mask, mbits);

  // 392 m-tiles = 8 XCDs * 49; GEMM1: 6 n-tiles of 256, GEMM2: 2 n-tiles
  gemm_kernel<0, 6, 49><<<2352, 512, 131072, stream>>>(xbf, wqkvb, b_qkv, qkv, 1536);
  attn_kernel<<<8192, 256, 0, stream>>>(qkv, pbb, mbits, xbf);
  gemm_kernel<1, 2, 49><<<784, 512, 131072, stream>>>(xbf, wprojb, b_proj, d_out, 512);
}